// Round 14
// baseline (447.873 us; speedup 1.0000x reference)
//
#include <hip/hip_runtime.h>
#include <hip/hip_bf16.h>

typedef __hip_bfloat16 bf16;

#define Bn   16
#define Nn   4096
#define NPn  1024
#define Kn   32
#define CINn 128
#define CGn  131
#define Cn   256
#define Hn   4
#define KPAD 160   // qkv K padded to 5x32 (internal order: feat 0..127, xyz 128..130)
#define XBS  168   // Xb (bf16) row stride (32 rows = 1 point)
#define XFS2 136   // raw (bf16) row stride
#define GFS  136   // gfmax row stride (bf16), pads zeroed

typedef __attribute__((ext_vector_type(8))) short frag_ab;   // 8 bf16
typedef __attribute__((ext_vector_type(4))) float frag_cd;   // 4 fp32

__device__ __forceinline__ float b2f(bf16 x) { return __bfloat162float(x); }
__device__ __forceinline__ bf16  f2b(float x) { return __float2bfloat16(x); }
__device__ __forceinline__ short f2bs(float x) {
  union { bf16 h; short s; } u; u.h = __float2bfloat16(x); return u.s;
}
__device__ __forceinline__ float bs2f(short s) {
  union { short v; bf16 h; } u; u.v = s; return __bfloat162float(u.h);
}
__device__ __forceinline__ unsigned f2ord(float f) {
  unsigned u = __float_as_uint(f);
  return u ^ ((u >> 31) ? 0xffffffffu : 0x80000000u);
}

// =====================================================================
// Kernel 0: pack xyz -> float4 (x,y,z,|x|^2). |x|^2 uses the IDENTICAL
// rounding chain knn uses inline -> knn keys stay bit-identical.
// =====================================================================
__global__ __launch_bounds__(256) void xyzw_prep_kernel(
    const float* __restrict__ xyz, float4* __restrict__ xyzw) {
  const int i = blockIdx.x * 256 + threadIdx.x;   // < Bn*Nn = 65536
  const float x = xyz[i*3 + 0];
  const float y = xyz[i*3 + 1];
  const float z = xyz[i*3 + 2];
  const float sx = __fadd_rn(__fadd_rn(__fmul_rn(x,x), __fmul_rn(y,y)),
                             __fmul_rn(z,z));
  xyzw[i] = make_float4(x, y, z, sx);
}

// =====================================================================
// Kernel 1: KNN — EXACT r16/r18 256-thread version (best measured).
// =====================================================================
__global__ __launch_bounds__(256) void knn_kernel(const float4* __restrict__ xyzw,
                                                  const float* __restrict__ newxyz,
                                                  int* __restrict__ idx_out) {
  constexpr int CAP = 2048;
  __shared__ unsigned long long tmin[256];
  __shared__ __align__(16) unsigned long long cand[CAP + 4];
  __shared__ unsigned long long wtau[4];
  __shared__ unsigned long long wred[4];   // fallback path only
  __shared__ int scnt;
  const int bp  = blockIdx.x;
  const int b   = bp >> 10;
  const int tid = threadIdx.x;
  const float qx = newxyz[bp*3 + 0];
  const float qy = newxyz[bp*3 + 1];
  const float qz = newxyz[bp*3 + 2];
  const float sn = __fadd_rn(__fadd_rn(__fmul_rn(qx,qx), __fmul_rn(qy,qy)),
                             __fmul_rn(qz,qz));
  const float4* xb = xyzw + (size_t)b * Nn;
  unsigned long long key[16];
  unsigned long long lmin = ~0ull;
  #pragma unroll
  for (int s = 0; s < 16; ++s) {
    const int n = s*256 + tid;
    const float4 xw = xb[n];
    const float dot = __fadd_rn(__fadd_rn(__fmul_rn(qx,xw.x), __fmul_rn(qy,xw.y)),
                                __fmul_rn(qz,xw.z));
    const float d2 = __fadd_rn(__fsub_rn(sn, __fmul_rn(2.0f, dot)), xw.w);
    key[s] = ((unsigned long long)f2ord(d2) << 32) | (unsigned)n;
    if (key[s] < lmin) lmin = key[s];
  }
  const int lane = tid & 63, wv = tid >> 6;

  if (tid == 0) scnt = 0;
  tmin[tid] = lmin;
  __syncthreads();

  // rank my thread-min within my wave's 64 thread-mins (broadcast reads)
  {
    const unsigned long long* wt = &tmin[wv * 64];
    int rk = 0;
    #pragma unroll 8
    for (int j = 0; j < 64; ++j) rk += (wt[j] < lmin) ? 1 : 0;
    if (rk == 15) wtau[wv] = lmin;   // per-wave 16th-smallest (keys unique)
  }
  __syncthreads();
  unsigned long long tau = wtau[0];
  if (wtau[1] < tau) tau = wtau[1];
  if (wtau[2] < tau) tau = wtau[2];
  if (wtau[3] < tau) tau = wtau[3];

  // compact candidates (keys <= tau)
  #pragma unroll
  for (int s = 0; s < 16; ++s) {
    if (key[s] <= tau) {
      const int p = atomicAdd(&scnt, 1);
      if (p < CAP) cand[p] = key[s];
    }
  }
  __syncthreads();
  const int m = scnt;

  if (m >= Kn && m <= CAP) {
    if (tid < 4) cand[m + tid] = ~0ull;   // pad so rank loop can run in 4s
    __syncthreads();
    const int m4 = (m + 3) & ~3;
    for (int t = tid; t < m; t += 256) {
      const unsigned long long mykey = cand[t];
      int r = 0;
      for (int j = 0; j < m4; j += 4) {
        r += (cand[j+0] < mykey) ? 1 : 0;
        r += (cand[j+1] < mykey) ? 1 : 0;
        r += (cand[j+2] < mykey) ? 1 : 0;
        r += (cand[j+3] < mykey) ? 1 : 0;
      }
      if (r < Kn) idx_out[(size_t)bp*Kn + r] = (int)(mykey & 0xffffffffu);
    }
  } else {
    // fallback: original serial tournament (correct for any data)
    for (int s = 0; s < Kn; ++s) {
      unsigned long long mm = lmin;
      #pragma unroll
      for (int d = 32; d; d >>= 1) {
        const unsigned lo = __shfl_xor((unsigned)(mm & 0xffffffffu), d, 64);
        const unsigned hi = __shfl_xor((unsigned)(mm >> 32), d, 64);
        const unsigned long long o = ((unsigned long long)hi << 32) | lo;
        if (o < mm) mm = o;
      }
      if (lane == 0) wred[wv] = mm;
      __syncthreads();
      unsigned long long best = wred[0];
      if (wred[1] < best) best = wred[1];
      if (wred[2] < best) best = wred[2];
      if (wred[3] < best) best = wred[3];
      __syncthreads();
      const int n = (int)(best & 0xffffffffu);
      if (tid == 0) idx_out[(size_t)bp*Kn + s] = n;
      if ((n & 255) == tid) {
        const int slot = n >> 8;
        #pragma unroll
        for (int t = 0; t < 16; ++t) if (t == slot) key[t] = ~0ull;
        unsigned long long m2 = ~0ull;
        #pragma unroll
        for (int t = 0; t < 16; ++t) if (key[t] < m2) m2 = key[t];
        lmin = m2;
      }
    }
  }
}

// =====================================================================
// Kernel 1b: ALL weight pre-swizzles in one launch (segment dispatch).
// =====================================================================
__global__ __launch_bounds__(256) void wprep_all_kernel(
    const float* __restrict__ w_qkv, const float* __restrict__ proj_w,
    const float* __restrict__ dense_w, const float* __restrict__ fc1_w,
    const float* __restrict__ fc2_w, short* __restrict__ o_qkv,
    short* __restrict__ o_proj, short* __restrict__ o_dense,
    short* __restrict__ o_fc1, short* __restrict__ o_fc2) {
  const int blk = blockIdx.x;
  const float* W; short* out; int K, N, nnt, remap, base;
  if      (blk <  480) { W=w_qkv;   out=o_qkv;   K=CGn; N=768; nnt=48; remap=1; base=0;    }
  else if (blk <  736) { W=proj_w;  out=o_proj;  K=Cn;  N=256; nnt=16; remap=0; base=480;  }
  else if (blk <  896) { W=dense_w; out=o_dense; K=CGn; N=256; nnt=16; remap=1; base=736;  }
  else if (blk < 1408) { W=fc1_w;   out=o_fc1;   K=Cn;  N=512; nnt=32; remap=0; base=896;  }
  else                 { W=fc2_w;   out=o_fc2;   K=512; N=256; nnt=16; remap=0; base=1408; }
  const int t = (blk - base) * 256 + threadIdx.x;
  const int j    = t & 7;
  const int lane = (t >> 3) & 63;
  const int nt   = (t >> 9) % nnt;
  const int kt   = (t >> 9) / nnt;
  const int k = kt*32 + (lane >> 4)*8 + j;
  const int n = nt*16 + (lane & 15);
  int krow = k;
  if (remap) krow = (k < 128) ? k + 3 : k - 128;
  out[t] = (k < K) ? f2bs(W[(size_t)krow*N + n]) : (short)0;
}

// =====================================================================
// Kernel 2: fused gather + gf_max + LN1 + MFMA qkv + attention.
// r22 (resubmit — r13 bench was an infra failure, no measurement).
// ONE point per block. r21 diagnosis: latency-bound at 3 blocks/CU
// with ~8-slot/thread residual spill. Halving per-block state: gather
// r[4] (16 VGPR), acc[4][2] (32), Xs 32 rows (~12KB LDS) -> live set
// ~100 regs fits __launch_bounds__(256,4) = 128-reg budget = 4
// blocks/CU, 16 waves, spill-free. Total MFMA unchanged; wfrag
// re-reads double but stay L2-resident. Go/no-go: WRITE_SIZE -> ~13MB.
// =====================================================================
__global__ __launch_bounds__(256, 4) void fused_attn_kernel(
    const float* __restrict__ xyz, const float* __restrict__ newxyz,
    const float* __restrict__ featin, const short* __restrict__ wfrag,
    const float* __restrict__ n1g, const float* __restrict__ n1b,
    const int* __restrict__ idx, bf16* __restrict__ attnout,
    bf16* __restrict__ gfmax) {
  __shared__ __align__(16) short Xs[32 * XBS];   // union: raw (32x136) -> Xb (32x168)
  __shared__ float sg[CGn], sb[CGn];
  __shared__ int sidx[32];
  const int bp  = blockIdx.x;    // one point per block
  const int b   = bp >> 10;
  const int tid = threadIdx.x;
  if (tid < 32) {
    int n = idx[(size_t)bp*Kn + tid];
    sidx[tid] = ((unsigned)n < (unsigned)Nn) ? n : 0;
  }
  if (tid < CGn) {   // LN params, ref->internal: internal j<128 = ref j+3
    const int rj = (tid < 128) ? tid + 3 : tid - 128;
    sg[tid] = n1g[rj];
    sb[tid] = n1b[rj];
  }
  __syncthreads();
  // ---- gather into registers: thread (kk,sub) holds 16 floats ----
  const int kk = tid >> 3, sub = tid & 7;   // kk 0..31, sub 0..7
  float4 r[4];
  float ex = 0.f;
  {
    const float* frow = featin + ((size_t)b*Nn + sidx[kk])*CINn;
    #pragma unroll
    for (int i = 0; i < 4; ++i) r[i] = *(const float4*)(frow + sub*4 + 32*i);
    if (sub < 3)
      ex = xyz[((size_t)b*Nn + sidx[kk])*3 + sub] - newxyz[bp*3 + sub];
  }
  // raw bf16 -> Xs (stride XFS2) for gfmax
  #pragma unroll
  for (int i = 0; i < 4; ++i) {
    short4 s4 = { f2bs(r[i].x), f2bs(r[i].y), f2bs(r[i].z), f2bs(r[i].w) };
    *(short4*)&Xs[kk*XFS2 + sub*4 + 32*i] = s4;
  }
  if (sub < 3) Xs[kk*XFS2 + 128 + sub] = f2bs(ex);
  // LN stats from raw fp32 registers (8-lane shuffle reduce over sub)
  float mean, rstd;
  {
    float s = ex, s2 = ex*ex;
    #pragma unroll
    for (int i = 0; i < 4; ++i) {
      s  += r[i].x + r[i].y + r[i].z + r[i].w;
      s2 += r[i].x*r[i].x + r[i].y*r[i].y + r[i].z*r[i].z + r[i].w*r[i].w;
    }
    s  += __shfl_xor(s, 1, 64);  s  += __shfl_xor(s, 2, 64);  s  += __shfl_xor(s, 4, 64);
    s2 += __shfl_xor(s2, 1, 64); s2 += __shfl_xor(s2, 2, 64); s2 += __shfl_xor(s2, 4, 64);
    mean = s * (1.0f/CGn);
    const float var = s2 * (1.0f/CGn) - mean*mean;
    rstd = rsqrtf(var + 1e-3f);
  }
  __syncthreads();
  // gf_max from raw bf16 (max is monotone under rounding -> bit-exact)
  if (tid < GFS) {
    float m = 0.f;
    if (tid < CGn) {
      m = -1e30f;
      #pragma unroll
      for (int k2 = 0; k2 < Kn; ++k2)
        m = fmaxf(m, bs2f(Xs[k2*XFS2 + tid]));
    }
    gfmax[(size_t)bp*GFS + tid] = f2b(m);
  }
  __syncthreads();   // raw buffer dead; overlay Xb
  // normalized bf16 -> Xs (Xb layout, stride XBS) from registers
  #pragma unroll
  for (int i = 0; i < 4; ++i) {
    const float4 g4 = *(const float4*)&sg[sub*4 + 32*i];
    const float4 b4 = *(const float4*)&sb[sub*4 + 32*i];
    short4 s4;
    s4.x = f2bs((r[i].x - mean)*rstd*g4.x + b4.x);
    s4.y = f2bs((r[i].y - mean)*rstd*g4.y + b4.y);
    s4.z = f2bs((r[i].z - mean)*rstd*g4.z + b4.z);
    s4.w = f2bs((r[i].w - mean)*rstd*g4.w + b4.w);
    *(short4*)&Xs[kk*XBS + sub*4 + 32*i] = s4;
  }
  if (sub < 3)
    Xs[kk*XBS + 128 + sub] = f2bs((ex - mean)*rstd*sg[128+sub] + sb[128+sub]);
  // zero-pad j in [131,160) for all 32 rows
  #pragma unroll
  for (int u = 0; u < 4; ++u) {
    const int e = u*256 + tid;
    const int row = e >> 5, jj = 131 + (e & 31);
    if (jj < 160) Xs[row*XBS + jj] = 0;
  }
  __syncthreads();
  // ---- MFMA passes: part 0 (Q) -> 1 (K) -> 2 (V); 2 M-tiles = 1 point ----
  const int lane = tid & 63, w = tid >> 6;
  const int col = lane & 15, quad = lane >> 4;
  float qm[4], aw[2][4], inv;
  // pass Q
  {
    frag_cd acc[4][2] = {};   // [ntl][mt]
    for (int kt = 0; kt < 5; ++kt) {
      const int ko = kt*32 + quad*8;
      frag_ab a[2];
      #pragma unroll
      for (int mt = 0; mt < 2; ++mt)
        a[mt] = *(const frag_ab*)&Xs[(mt*16 + col)*XBS + ko];
      #pragma unroll
      for (int ntl = 0; ntl < 4; ++ntl) {
        const int nt = w*4 + ntl;   // part 0
        const frag_ab bfr = *(const frag_ab*)(wfrag + ((size_t)(kt*48 + nt)*64 + lane)*8);
        #pragma unroll
        for (int mt = 0; mt < 2; ++mt)
          acc[ntl][mt] = __builtin_amdgcn_mfma_f32_16x16x32_bf16(a[mt], bfr, acc[ntl][mt], 0, 0, 0);
      }
    }
    #pragma unroll
    for (int ntl = 0; ntl < 4; ++ntl) {
      float m = -1e30f;
      #pragma unroll
      for (int mt = 0; mt < 2; ++mt)
        #pragma unroll
        for (int rr = 0; rr < 4; ++rr) m = fmaxf(m, acc[ntl][mt][rr]);
      m = fmaxf(m, __shfl_xor(m, 16, 64));
      m = fmaxf(m, __shfl_xor(m, 32, 64));
      qm[ntl] = m;
    }
  }
  // pass K -> logits -> softmax weights
  {
    frag_cd acc[4][2] = {};
    for (int kt = 0; kt < 5; ++kt) {
      const int ko = kt*32 + quad*8;
      frag_ab a[2];
      #pragma unroll
      for (int mt = 0; mt < 2; ++mt)
        a[mt] = *(const frag_ab*)&Xs[(mt*16 + col)*XBS + ko];
      #pragma unroll
      for (int ntl = 0; ntl < 4; ++ntl) {
        const int nt = 16 + w*4 + ntl;   // part 1
        const frag_ab bfr = *(const frag_ab*)(wfrag + ((size_t)(kt*48 + nt)*64 + lane)*8);
        #pragma unroll
        for (int mt = 0; mt < 2; ++mt)
          acc[ntl][mt] = __builtin_amdgcn_mfma_f32_16x16x32_bf16(a[mt], bfr, acc[ntl][mt], 0, 0, 0);
      }
    }
    float lg[2][4];
    #pragma unroll
    for (int mtl = 0; mtl < 2; ++mtl)
      #pragma unroll
      for (int rr = 0; rr < 4; ++rr) {
        float pp = 0.f;
        #pragma unroll
        for (int ntl = 0; ntl < 4; ++ntl) pp = fmaf(qm[ntl], acc[ntl][mtl][rr], pp);
        #pragma unroll
        for (int d = 1; d < 16; d <<= 1) pp += __shfl_xor(pp, d, 64);
        lg[mtl][rr] = pp * 0.0625f;
      }
    float mx = -1e30f;
    #pragma unroll
    for (int mtl = 0; mtl < 2; ++mtl)
      #pragma unroll
      for (int rr = 0; rr < 4; ++rr) mx = fmaxf(mx, lg[mtl][rr]);
    mx = fmaxf(mx, __shfl_xor(mx, 16, 64));
    mx = fmaxf(mx, __shfl_xor(mx, 32, 64));
    float ssum = 0.f;
    #pragma unroll
    for (int mtl = 0; mtl < 2; ++mtl)
      #pragma unroll
      for (int rr = 0; rr < 4; ++rr) { aw[mtl][rr] = expf(lg[mtl][rr] - mx); ssum += aw[mtl][rr]; }
    ssum += __shfl_xor(ssum, 16, 64);
    ssum += __shfl_xor(ssum, 32, 64);
    inv = 1.f / ssum;
  }
  // pass V -> output
  {
    frag_cd acc[4][2] = {};
    for (int kt = 0; kt < 5; ++kt) {
      const int ko = kt*32 + quad*8;
      frag_ab a[2];
      #pragma unroll
      for (int mt = 0; mt < 2; ++mt)
        a[mt] = *(const frag_ab*)&Xs[(mt*16 + col)*XBS + ko];
      #pragma unroll
      for (int ntl = 0; ntl < 4; ++ntl) {
        const int nt = 32 + w*4 + ntl;   // part 2
        const frag_ab bfr = *(const frag_ab*)(wfrag + ((size_t)(kt*48 + nt)*64 + lane)*8);
        #pragma unroll
        for (int mt = 0; mt < 2; ++mt)
          acc[ntl][mt] = __builtin_amdgcn_mfma_f32_16x16x32_bf16(a[mt], bfr, acc[ntl][mt], 0, 0, 0);
      }
    }
    #pragma unroll
    for (int ntl = 0; ntl < 4; ++ntl) {
      float o = 0.f;
      #pragma unroll
      for (int mtl = 0; mtl < 2; ++mtl)
        #pragma unroll
        for (int rr = 0; rr < 4; ++rr) o = fmaf(aw[mtl][rr], acc[ntl][mtl][rr], o);
      o += __shfl_xor(o, 16, 64);
      o += __shfl_xor(o, 32, 64);
      if (quad == 0)
        attnout[(size_t)bp*Cn + w*64 + ntl*16 + col] = f2b(o * inv);
    }
  }
}

// =====================================================================
// Kernel 3: MFMA GEMM, 64x128 tile (unchanged from r7/r8).
// =====================================================================
template<bool RELU, bool ADD_S, bool OUT_BF16>
__global__ __launch_bounds__(256) void mfma_gemm_kernel(
    const bf16* __restrict__ A, int lda, int Ka,
    const short* __restrict__ Wf, int nnt_total, int N,
    const float* __restrict__ bias, const bf16* __restrict__ S,
    void* __restrict__ Dv) {
  __shared__ __align__(16) short As[64*40];
  const int m0 = blockIdx.y * 64;
  const int n0 = blockIdx.x * 128;
  const int tid = threadIdx.x, lane = tid & 63, w = tid >> 6;
  const int col = lane & 15, quad = lane >> 4;
  const int row = tid >> 2, c8 = (tid & 3) * 8;
  frag_cd acc[4][2] = {};
  const int nkt = (Ka + 31) >> 5;
  for (int kt = 0; kt < nkt; ++kt) {
    const int k0 = kt*32 + c8;
    frag_ab av = {0,0,0,0,0,0,0,0};
    if (k0 + 8 <= Ka)
      av = *(const frag_ab*)((const short*)A + (size_t)(m0+row)*lda + k0);
    __syncthreads();
    *(frag_ab*)&As[row*40 + c8] = av;
    __syncthreads();
    frag_ab afr[4];
    #pragma unroll
    for (int mt = 0; mt < 4; ++mt)
      afr[mt] = *(const frag_ab*)&As[(mt*16 + col)*40 + quad*8];
    #pragma unroll
    for (int ntl = 0; ntl < 2; ++ntl) {
      const int nt = (n0 >> 4) + w*2 + ntl;
      const frag_ab bfr = *(const frag_ab*)(Wf + ((size_t)(kt*nnt_total + nt)*64 + lane)*8);
      #pragma unroll
      for (int mt = 0; mt < 4; ++mt)
        acc[mt][ntl] = __builtin_amdgcn_mfma_f32_16x16x32_bf16(afr[mt], bfr, acc[mt][ntl], 0, 0, 0);
    }
  }
  #pragma unroll
  for (int ntl = 0; ntl < 2; ++ntl) {
    const int n = n0 + w*32 + ntl*16 + col;
    const float bv = bias[n];
    #pragma unroll
    for (int mt = 0; mt < 4; ++mt) {
      #pragma unroll
      for (int r = 0; r < 4; ++r) {
        const int m = m0 + mt*16 + quad*4 + r;
        float v = acc[mt][ntl][r] + bv;
        if (RELU) v = fmaxf(v, 0.f);
        if (ADD_S) v += b2f(S[(size_t)m*N + n]);
        if (OUT_BF16) ((bf16*)Dv)[(size_t)m*N + n] = f2b(v);
        else          ((float*)Dv)[(size_t)m*N + n] = v;
      }
    }
  }
}

// =====================================================================
// Kernel 3b: dual GEMM (proj + dense fused), 64x128 tile, 512 blocks.
// =====================================================================
__global__ __launch_bounds__(256) void dual_gemm_kernel(
    const bf16* __restrict__ A1, const short* __restrict__ W1,
    const bf16* __restrict__ A2, const short* __restrict__ W2,
    const float* __restrict__ b1, const float* __restrict__ b2,
    bf16* __restrict__ D) {
  __shared__ __align__(16) short As[64*40];
  const int m0 = blockIdx.y * 64;
  const int n0 = blockIdx.x * 128;
  const int tid = threadIdx.x, lane = tid & 63, w = tid >> 6;
  const int col = lane & 15, quad = lane >> 4;
  const int row = tid >> 2, c8 = (tid & 3) * 8;
  frag_cd acc1[4][2] = {}, acc2[4][2] = {};
  for (int kt = 0; kt < 8; ++kt) {
    const frag_ab av = *(const frag_ab*)((const short*)A1 + (size_t)(m0+row)*Cn + kt*32 + c8);
    __syncthreads();
    *(frag_ab*)&As[row*40 + c8] = av;
    __syncthreads();
    frag_ab afr[4];
    #pragma unroll
    for (int mt = 0; mt < 4; ++mt)
      afr[mt] = *(const frag_ab*)&As[(mt*16 + col)*40 + quad*8];
    #pragma unroll
    for (int ntl = 0; ntl < 2; ++ntl) {
      const int nt = (n0 >> 4) + w*2 + ntl;
      const frag_ab bfr = *(const frag_ab*)(W1 + ((size_t)(kt*16 + nt)*64 + lane)*8);
      #pragma unroll
      for (int mt = 0; mt < 4; ++mt)
        acc1[mt][ntl] = __builtin_amdgcn_mfma_f32_16x16x32_bf16(afr[mt], bfr, acc1[mt][ntl], 0, 0, 0);
    }
  }
  for (int kt = 0; kt < 5; ++kt) {
    const int k0 = kt*32 + c8;
    frag_ab av = {0,0,0,0,0,0,0,0};
    if (k0 + 8 <= GFS)
      av = *(const frag_ab*)((const short*)A2 + (size_t)(m0+row)*GFS + k0);
    __syncthreads();
    *(frag_ab*)&As[row*40 + c8] = av;
    __syncthreads();
    frag_ab afr[4];
    #pragma unroll
    for (int mt = 0; mt < 4; ++mt)
      afr[mt] = *(const frag_ab*)&As[(mt*16 + col)*40 + quad*8];
    #pragma unroll
    for (int ntl = 0; ntl < 2; ++ntl) {
      const int nt = (n0 >> 4) + w*2 + ntl;
      const frag_ab bfr = *(const frag_ab*)(W2 + ((size_t)(kt*16 + nt)*64 + lane)*8);
      #pragma unroll
      for (int mt = 0; mt < 4; ++mt)
        acc2[mt][ntl] = __builtin_amdgcn_mfma_f32_16x16x32_bf16(afr[mt], bfr, acc2[mt][ntl], 0, 0, 0);
    }
  }
  #pragma unroll
  for (int ntl = 0; ntl < 2; ++ntl) {
    const int n = n0 + w*32 + ntl*16 + col;
    const float bv1 = b1[n], bv2 = b2[n];
    #pragma unroll
    for (int mt = 0; mt < 4; ++mt) {
      #pragma unroll
      for (int r = 0; r < 4; ++r) {
        const int m = m0 + mt*16 + quad*4 + r;
        const float v = fmaxf(acc1[mt][ntl][r] + bv1, 0.f)
                      + fmaxf(acc2[mt][ntl][r] + bv2, 0.f);
        D[(size_t)m*Cn + n] = f2b(v);
      }
    }
  }
}

// =====================================================================
// Kernel 4: LayerNorm2 over C=256, 4 rows/block (separate — measured
// faster than fusing into dual_gemm, r20 post-mortem).
// =====================================================================
__global__ __launch_bounds__(256) void ln2_kernel(const bf16* __restrict__ feat,
                                                  const float* __restrict__ g,
                                                  const float* __restrict__ b,
                                                  bf16* __restrict__ out) {
  const int r = blockIdx.x*4 + (threadIdx.x >> 6), lane = threadIdx.x & 63;
  float vv[4];
  #pragma unroll
  for (int c = 0; c < 4; ++c) vv[c] = b2f(feat[(size_t)r*Cn + lane*4 + c]);
  float s  = vv[0] + vv[1] + vv[2] + vv[3];
  float s2 = vv[0]*vv[0] + vv[1]*vv[1] + vv[2]*vv[2] + vv[3]*vv[3];
  #pragma unroll
  for (int d = 32; d; d >>= 1) { s += __shfl_xor(s, d, 64); s2 += __shfl_xor(s2, d, 64); }
  const float mean = s * (1.f/256.f);
  const float var  = s2 * (1.f/256.f) - mean*mean;
  const float rstd = rsqrtf(var + 1e-3f);
  #pragma unroll
  for (int c = 0; c < 4; ++c) {
    const int cc = lane*4 + c;
    out[(size_t)r*Cn + cc] = f2b((vv[c] - mean)*rstd*g[cc] + b[cc]);
  }
}

// =====================================================================
// kernel_launch — fp32 in/out. Workspace (peak 41.16 MB < 41.94 proven):
//   wqkv@0 245,760 | wproj@245,760 131,072 | wdense@376,832 81,920
//   wfc1@458,752 262,144 | wfc2@720,896 262,144 | pad to 1 MiB
//   featB  bf16 [16384*256] @  1,048,576   8 MiB  residual, live to end
//   attnA  bf16 [16384*256] @  9,437,184   8 MiB  attnout -> ln2out
//   gfmax  bf16 [16384*136] @ 17,825,792   4.46 MiB } dead before fc1
//   idx    int  [16384*32]  @ 22,282,240   2 MiB    } fc1out overlays
//   fc1out bf16 [16384*512] @ 24,379,392  16 MiB  (ends 41,156,608)
//   xyzw   f4   [65536]     @ 24,379,392   1 MiB  (lifetime: prep+knn
//                                                  only; fc1out written
//                                                  much later — no clash)
// =====================================================================
extern "C" void kernel_launch(void* const* d_in, const int* in_sizes, int n_in,
                              void* d_out, int out_size, void* d_ws, size_t ws_size,
                              hipStream_t stream) {
  const float* xyz     = (const float*)d_in[0];
  const float* newxyz  = (const float*)d_in[1];
  const float* featin  = (const float*)d_in[2];
  const float* w_qkv   = (const float*)d_in[3];
  const float* proj_w  = (const float*)d_in[4];
  const float* proj_b  = (const float*)d_in[5];
  const float* dense_w = (const float*)d_in[6];
  const float* dense_b = (const float*)d_in[7];
  const float* fc1_w   = (const float*)d_in[8];
  const float* fc1_b   = (const float*)d_in[9];
  const float* fc2_w   = (const float*)d_in[10];
  const float* fc2_b   = (const float*)d_in[11];
  const float* n1g     = (const float*)d_in[12];
  const float* n1b     = (const float*)d_in[13];
  const float* n2g     = (const float*)d_in[14];
  const float* n2b     = (const float*)d_in[15];

  char*  ws     = (char*)d_ws;
  short* wqkv   = (short*)(ws + 0);
  short* wproj  = (short*)(ws + 245760);
  short* wdense = (short*)(ws + 376832);
  short* wfc1   = (short*)(ws + 458752);
  short* wfc2   = (short*)(ws + 720896);
  bf16*  featB  = (bf16*)(ws + 1048576);
  bf16*  attnA  = (bf16*)(ws + 9437184);
  bf16*  gfmax  = (bf16*)(ws + 17825792);
  int*   idxws  = (int*) (ws + 22282240);
  bf16*  fc1out = (bf16*)(ws + 24379392);
  float4* xyzw  = (float4*)(ws + 24379392);   // overlays fc1out (disjoint lifetime)

  const int M = Bn * NPn;  // 16384

  xyzw_prep_kernel<<<dim3(Bn*Nn/256), dim3(256), 0, stream>>>(xyz, xyzw);
  knn_kernel<<<dim3(M), dim3(256), 0, stream>>>(xyzw, newxyz, idxws);
  wprep_all_kernel<<<dim3(1920), dim3(256), 0, stream>>>(
      w_qkv, proj_w, dense_w, fc1_w, fc2_w, wqkv, wproj, wdense, wfc1, wfc2);

  fused_attn_kernel<<<dim3(M), dim3(256), 0, stream>>>(
      xyz, newxyz, featin, wqkv, n1g, n1b, idxws, attnA, gfmax);
  // featB = relu(attn@proj + pb) + relu(gfmax@dense + db)
  dual_gemm_kernel<<<dim3(2, M/64), dim3(256), 0, stream>>>(
      attnA, wproj, gfmax, wdense, proj_b, dense_b, featB);
  // attnA <- LN2(featB)
  ln2_kernel<<<dim3(M/4), dim3(256), 0, stream>>>(featB, n2g, n2b, attnA);
  // fc1out = relu(attnA @ fc1 + b1)
  mfma_gemm_kernel<true, false, true><<<dim3(4, M/64), dim3(256), 0, stream>>>(
      attnA, Cn, Cn, wfc1, 32, 512, fc1_b, (const bf16*)nullptr, fc1out);
  // out = fc1out @ fc2 + b2 + featB   (fp32 output)
  mfma_gemm_kernel<false, true, false><<<dim3(2, M/64), dim3(256), 0, stream>>>(
      fc1out, 512, 512, wfc2, 16, Cn, fc2_b, featB, d_out);
}

// Round 15
// 416.610 us; speedup vs baseline: 1.0750x; 1.0750x over previous
//
#include <hip/hip_runtime.h>
#include <hip/hip_bf16.h>

typedef __hip_bfloat16 bf16;

#define Bn   16
#define Nn   4096
#define NPn  1024
#define Kn   32
#define CINn 128
#define CGn  131
#define Cn   256
#define Hn   4
#define KPAD 160   // qkv K padded to 5x32 (internal order: feat 0..127, xyz 128..130)
#define XBS  168   // Xb (bf16) row stride (64 rows = 2 points)
#define XFS2 136   // raw (bf16) row stride
#define GFS  136   // gfmax row stride (bf16), pads zeroed

typedef __attribute__((ext_vector_type(8))) short frag_ab;   // 8 bf16
typedef __attribute__((ext_vector_type(4))) float frag_cd;   // 4 fp32

__device__ __forceinline__ float b2f(bf16 x) { return __bfloat162float(x); }
__device__ __forceinline__ bf16  f2b(float x) { return __float2bfloat16(x); }
__device__ __forceinline__ short f2bs(float x) {
  union { bf16 h; short s; } u; u.h = __float2bfloat16(x); return u.s;
}
__device__ __forceinline__ float bs2f(short s) {
  union { short v; bf16 h; } u; u.v = s; return __bfloat162float(u.h);
}
__device__ __forceinline__ unsigned f2ord(float f) {
  unsigned u = __float_as_uint(f);
  return u ^ ((u >> 31) ? 0xffffffffu : 0x80000000u);
}

// =====================================================================
// Kernel 0: pack xyz -> float4 (x,y,z,|x|^2). |x|^2 uses the IDENTICAL
// rounding chain knn uses inline -> knn keys stay bit-identical.
// =====================================================================
__global__ __launch_bounds__(256) void xyzw_prep_kernel(
    const float* __restrict__ xyz, float4* __restrict__ xyzw) {
  const int i = blockIdx.x * 256 + threadIdx.x;   // < Bn*Nn = 65536
  const float x = xyz[i*3 + 0];
  const float y = xyz[i*3 + 1];
  const float z = xyz[i*3 + 2];
  const float sx = __fadd_rn(__fadd_rn(__fmul_rn(x,x), __fmul_rn(y,y)),
                             __fmul_rn(z,z));
  xyzw[i] = make_float4(x, y, z, sx);
}

// =====================================================================
// Kernel 1: KNN — EXACT r16/r18 256-thread version (best measured;
// G=8, 512-thread both regressed). tau = per-wave 16th-smallest;
// m>=Kn guard makes any tau safe; rare m<32 takes the exact fallback.
// =====================================================================
__global__ __launch_bounds__(256) void knn_kernel(const float4* __restrict__ xyzw,
                                                  const float* __restrict__ newxyz,
                                                  int* __restrict__ idx_out) {
  constexpr int CAP = 2048;
  __shared__ unsigned long long tmin[256];
  __shared__ __align__(16) unsigned long long cand[CAP + 4];
  __shared__ unsigned long long wtau[4];
  __shared__ unsigned long long wred[4];   // fallback path only
  __shared__ int scnt;
  const int bp  = blockIdx.x;
  const int b   = bp >> 10;
  const int tid = threadIdx.x;
  const float qx = newxyz[bp*3 + 0];
  const float qy = newxyz[bp*3 + 1];
  const float qz = newxyz[bp*3 + 2];
  const float sn = __fadd_rn(__fadd_rn(__fmul_rn(qx,qx), __fmul_rn(qy,qy)),
                             __fmul_rn(qz,qz));
  const float4* xb = xyzw + (size_t)b * Nn;
  unsigned long long key[16];
  unsigned long long lmin = ~0ull;
  #pragma unroll
  for (int s = 0; s < 16; ++s) {
    const int n = s*256 + tid;
    const float4 xw = xb[n];
    const float dot = __fadd_rn(__fadd_rn(__fmul_rn(qx,xw.x), __fmul_rn(qy,xw.y)),
                                __fmul_rn(qz,xw.z));
    const float d2 = __fadd_rn(__fsub_rn(sn, __fmul_rn(2.0f, dot)), xw.w);
    key[s] = ((unsigned long long)f2ord(d2) << 32) | (unsigned)n;
    if (key[s] < lmin) lmin = key[s];
  }
  const int lane = tid & 63, wv = tid >> 6;

  if (tid == 0) scnt = 0;
  tmin[tid] = lmin;
  __syncthreads();

  // rank my thread-min within my wave's 64 thread-mins (broadcast reads)
  {
    const unsigned long long* wt = &tmin[wv * 64];
    int rk = 0;
    #pragma unroll 8
    for (int j = 0; j < 64; ++j) rk += (wt[j] < lmin) ? 1 : 0;
    if (rk == 15) wtau[wv] = lmin;   // per-wave 16th-smallest (keys unique)
  }
  __syncthreads();
  unsigned long long tau = wtau[0];
  if (wtau[1] < tau) tau = wtau[1];
  if (wtau[2] < tau) tau = wtau[2];
  if (wtau[3] < tau) tau = wtau[3];

  // compact candidates (keys <= tau)
  #pragma unroll
  for (int s = 0; s < 16; ++s) {
    if (key[s] <= tau) {
      const int p = atomicAdd(&scnt, 1);
      if (p < CAP) cand[p] = key[s];
    }
  }
  __syncthreads();
  const int m = scnt;

  if (m >= Kn && m <= CAP) {
    if (tid < 4) cand[m + tid] = ~0ull;   // pad so rank loop can run in 4s
    __syncthreads();
    const int m4 = (m + 3) & ~3;
    for (int t = tid; t < m; t += 256) {
      const unsigned long long mykey = cand[t];
      int r = 0;
      for (int j = 0; j < m4; j += 4) {
        r += (cand[j+0] < mykey) ? 1 : 0;
        r += (cand[j+1] < mykey) ? 1 : 0;
        r += (cand[j+2] < mykey) ? 1 : 0;
        r += (cand[j+3] < mykey) ? 1 : 0;
      }
      if (r < Kn) idx_out[(size_t)bp*Kn + r] = (int)(mykey & 0xffffffffu);
    }
  } else {
    // fallback: original serial tournament (correct for any data)
    for (int s = 0; s < Kn; ++s) {
      unsigned long long mm = lmin;
      #pragma unroll
      for (int d = 32; d; d >>= 1) {
        const unsigned lo = __shfl_xor((unsigned)(mm & 0xffffffffu), d, 64);
        const unsigned hi = __shfl_xor((unsigned)(mm >> 32), d, 64);
        const unsigned long long o = ((unsigned long long)hi << 32) | lo;
        if (o < mm) mm = o;
      }
      if (lane == 0) wred[wv] = mm;
      __syncthreads();
      unsigned long long best = wred[0];
      if (wred[1] < best) best = wred[1];
      if (wred[2] < best) best = wred[2];
      if (wred[3] < best) best = wred[3];
      __syncthreads();
      const int n = (int)(best & 0xffffffffu);
      if (tid == 0) idx_out[(size_t)bp*Kn + s] = n;
      if ((n & 255) == tid) {
        const int slot = n >> 8;
        #pragma unroll
        for (int t = 0; t < 16; ++t) if (t == slot) key[t] = ~0ull;
        unsigned long long m2 = ~0ull;
        #pragma unroll
        for (int t = 0; t < 16; ++t) if (key[t] < m2) m2 = key[t];
        lmin = m2;
      }
    }
  }
}

// =====================================================================
// Kernel 1b: ALL weight pre-swizzles in one launch (segment dispatch).
// =====================================================================
__global__ __launch_bounds__(256) void wprep_all_kernel(
    const float* __restrict__ w_qkv, const float* __restrict__ proj_w,
    const float* __restrict__ dense_w, const float* __restrict__ fc1_w,
    const float* __restrict__ fc2_w, short* __restrict__ o_qkv,
    short* __restrict__ o_proj, short* __restrict__ o_dense,
    short* __restrict__ o_fc1, short* __restrict__ o_fc2) {
  const int blk = blockIdx.x;
  const float* W; short* out; int K, N, nnt, remap, base;
  if      (blk <  480) { W=w_qkv;   out=o_qkv;   K=CGn; N=768; nnt=48; remap=1; base=0;    }
  else if (blk <  736) { W=proj_w;  out=o_proj;  K=Cn;  N=256; nnt=16; remap=0; base=480;  }
  else if (blk <  896) { W=dense_w; out=o_dense; K=CGn; N=256; nnt=16; remap=1; base=736;  }
  else if (blk < 1408) { W=fc1_w;   out=o_fc1;   K=Cn;  N=512; nnt=32; remap=0; base=896;  }
  else                 { W=fc2_w;   out=o_fc2;   K=512; N=256; nnt=16; remap=0; base=1408; }
  const int t = (blk - base) * 256 + threadIdx.x;
  const int j    = t & 7;
  const int lane = (t >> 3) & 63;
  const int nt   = (t >> 9) % nnt;
  const int kt   = (t >> 9) / nnt;
  const int k = kt*32 + (lane >> 4)*8 + j;
  const int n = nt*16 + (lane & 15);
  int krow = k;
  if (remap) krow = (k < 128) ? k + 3 : k - 128;
  out[t] = (k < K) ? f2bs(W[(size_t)krow*N + n]) : (short)0;
}

// =====================================================================
// Kernel 2: fused gather + gf_max + LN1 + MFMA qkv + attention.
// EXACT r15 body (best measured: 192.2-196.4us). Final config notes:
// 2 points/block beats 1 point/block-spill-free (r22: 235us, WRITE
// 12.8MB clean but lost 2-point amortization); (256,3)+residual-spill
// beats (256,2)-no-spill (247us); setprio, Raw re-read, pipelining,
// in-reg gfmax all measured-rejected.
// =====================================================================
__global__ __launch_bounds__(256, 3) void fused_attn_kernel(
    const float* __restrict__ xyz, const float* __restrict__ newxyz,
    const float* __restrict__ featin, const short* __restrict__ wfrag,
    const float* __restrict__ n1g, const float* __restrict__ n1b,
    const int* __restrict__ idx, bf16* __restrict__ attnout,
    bf16* __restrict__ gfmax) {
  __shared__ __align__(16) short Xs[64 * XBS];   // union: raw (64x136) -> Xb (64x168)
  __shared__ float sg[CGn], sb[CGn];
  __shared__ int sidx[64];
  const int bp0 = blockIdx.x * 2;   // two points, same batch (1024 even)
  const int b   = bp0 >> 10;
  const int tid = threadIdx.x;
  if (tid < 64) {
    int n = idx[(size_t)bp0*Kn + tid];
    sidx[tid] = ((unsigned)n < (unsigned)Nn) ? n : 0;
  }
  if (tid < CGn) {   // LN params, ref->internal: internal j<128 = ref j+3
    const int rj = (tid < 128) ? tid + 3 : tid - 128;
    sg[tid] = n1g[rj];
    sb[tid] = n1b[rj];
  }
  __syncthreads();
  // ---- gather into registers: thread (kk,sub) holds 16 floats per point ----
  const int kk = tid >> 3, sub = tid & 7;
  float4 r[2][4];
  float ex[2] = {0.f, 0.f};
  #pragma unroll
  for (int p = 0; p < 2; ++p) {
    const int row = p*32 + kk;
    const float* frow = featin + ((size_t)b*Nn + sidx[row])*CINn;
    #pragma unroll
    for (int i = 0; i < 4; ++i) r[p][i] = *(const float4*)(frow + sub*4 + 32*i);
    if (sub < 3)
      ex[p] = xyz[((size_t)b*Nn + sidx[row])*3 + sub] - newxyz[(bp0+p)*3 + sub];
  }
  // raw bf16 -> Xs (stride XFS2) for gfmax
  #pragma unroll
  for (int p = 0; p < 2; ++p) {
    const int row = p*32 + kk;
    #pragma unroll
    for (int i = 0; i < 4; ++i) {
      short4 s4 = { f2bs(r[p][i].x), f2bs(r[p][i].y), f2bs(r[p][i].z), f2bs(r[p][i].w) };
      *(short4*)&Xs[row*XFS2 + sub*4 + 32*i] = s4;
    }
    if (sub < 3) Xs[row*XFS2 + 128 + sub] = f2bs(ex[p]);
  }
  // LN stats from raw fp32 registers (8-lane shuffle reduce)
  float mean[2], rstd[2];
  #pragma unroll
  for (int p = 0; p < 2; ++p) {
    float s = ex[p], s2 = ex[p]*ex[p];
    #pragma unroll
    for (int i = 0; i < 4; ++i) {
      s  += r[p][i].x + r[p][i].y + r[p][i].z + r[p][i].w;
      s2 += r[p][i].x*r[p][i].x + r[p][i].y*r[p][i].y
          + r[p][i].z*r[p][i].z + r[p][i].w*r[p][i].w;
    }
    s  += __shfl_xor(s, 1, 64);  s  += __shfl_xor(s, 2, 64);  s  += __shfl_xor(s, 4, 64);
    s2 += __shfl_xor(s2, 1, 64); s2 += __shfl_xor(s2, 2, 64); s2 += __shfl_xor(s2, 4, 64);
    mean[p] = s * (1.0f/CGn);
    const float var = s2 * (1.0f/CGn) - mean[p]*mean[p];
    rstd[p] = rsqrtf(var + 1e-3f);
  }
  __syncthreads();
  // gf_max from raw bf16 (max is monotone under rounding -> bit-exact)
  #pragma unroll
  for (int p = 0; p < 2; ++p) {
    if (tid < GFS) {
      float m = 0.f;
      if (tid < CGn) {
        m = -1e30f;
        #pragma unroll
        for (int k2 = 0; k2 < Kn; ++k2)
          m = fmaxf(m, bs2f(Xs[(p*32 + k2)*XFS2 + tid]));
      }
      gfmax[(size_t)(bp0+p)*GFS + tid] = f2b(m);
    }
  }
  __syncthreads();   // raw buffer dead; overlay Xb
  // normalized bf16 -> Xs (Xb layout, stride XBS) from registers
  #pragma unroll
  for (int p = 0; p < 2; ++p) {
    const int row = p*32 + kk;
    #pragma unroll
    for (int i = 0; i < 4; ++i) {
      const float4 g4 = *(const float4*)&sg[sub*4 + 32*i];
      const float4 b4 = *(const float4*)&sb[sub*4 + 32*i];
      short4 s4;
      s4.x = f2bs((r[p][i].x - mean[p])*rstd[p]*g4.x + b4.x);
      s4.y = f2bs((r[p][i].y - mean[p])*rstd[p]*g4.y + b4.y);
      s4.z = f2bs((r[p][i].z - mean[p])*rstd[p]*g4.z + b4.z);
      s4.w = f2bs((r[p][i].w - mean[p])*rstd[p]*g4.w + b4.w);
      *(short4*)&Xs[row*XBS + sub*4 + 32*i] = s4;
    }
    if (sub < 3)
      Xs[row*XBS + 128 + sub] = f2bs((ex[p] - mean[p])*rstd[p]*sg[128+sub] + sb[128+sub]);
  }
  // zero-pad j in [131,160) for all 64 rows
  #pragma unroll
  for (int u = 0; u < 8; ++u) {
    const int e = u*256 + tid;
    const int row = e >> 5, jj = 131 + (e & 31);
    if (jj < 160) Xs[row*XBS + jj] = 0;
  }
  __syncthreads();
  // ---- MFMA passes (ntl-split): part 0 (Q) -> 1 (K) -> 2 (V) ----
  const int lane = tid & 63, w = tid >> 6;
  const int col = lane & 15, quad = lane >> 4;
  float qm[2][4], aw[2][2][4], inv[2];
  // pass Q: two halves of 2 ntl; acc[2][4]
  {
    #pragma unroll 1
    for (int half = 0; half < 2; ++half) {
      frag_cd acc[2][4] = {};   // [ntl][mt]
      for (int kt = 0; kt < 5; ++kt) {
        const int ko = kt*32 + quad*8;
        frag_ab a[4];
        #pragma unroll
        for (int mt = 0; mt < 4; ++mt)
          a[mt] = *(const frag_ab*)&Xs[(mt*16 + col)*XBS + ko];
        #pragma unroll
        for (int ntl = 0; ntl < 2; ++ntl) {
          const int nt = w*4 + half*2 + ntl;   // part 0
          const frag_ab bfr = *(const frag_ab*)(wfrag + ((size_t)(kt*48 + nt)*64 + lane)*8);
          #pragma unroll
          for (int mt = 0; mt < 4; ++mt)
            acc[ntl][mt] = __builtin_amdgcn_mfma_f32_16x16x32_bf16(a[mt], bfr, acc[ntl][mt], 0, 0, 0);
        }
      }
      #pragma unroll
      for (int p = 0; p < 2; ++p)
        #pragma unroll
        for (int ntl = 0; ntl < 2; ++ntl) {
          float m = -1e30f;
          #pragma unroll
          for (int mtl = 0; mtl < 2; ++mtl)
            #pragma unroll
            for (int rr = 0; rr < 4; ++rr) m = fmaxf(m, acc[ntl][p*2+mtl][rr]);
          m = fmaxf(m, __shfl_xor(m, 16, 64));
          m = fmaxf(m, __shfl_xor(m, 32, 64));
          qm[p][half*2 + ntl] = m;
        }
    }
  }
  // pass K: two halves; partial logits pp carried across halves
  {
    float pp[2][2][4] = {};   // [p][mtl][rr], pre lane-reduce
    #pragma unroll 1
    for (int half = 0; half < 2; ++half) {
      frag_cd acc[2][4] = {};
      for (int kt = 0; kt < 5; ++kt) {
        const int ko = kt*32 + quad*8;
        frag_ab a[4];
        #pragma unroll
        for (int mt = 0; mt < 4; ++mt)
          a[mt] = *(const frag_ab*)&Xs[(mt*16 + col)*XBS + ko];
        #pragma unroll
        for (int ntl = 0; ntl < 2; ++ntl) {
          const int nt = 16 + w*4 + half*2 + ntl;   // part 1
          const frag_ab bfr = *(const frag_ab*)(wfrag + ((size_t)(kt*48 + nt)*64 + lane)*8);
          #pragma unroll
          for (int mt = 0; mt < 4; ++mt)
            acc[ntl][mt] = __builtin_amdgcn_mfma_f32_16x16x32_bf16(a[mt], bfr, acc[ntl][mt], 0, 0, 0);
        }
      }
      #pragma unroll
      for (int p = 0; p < 2; ++p)
        #pragma unroll
        for (int mtl = 0; mtl < 2; ++mtl)
          #pragma unroll
          for (int rr = 0; rr < 4; ++rr) {
            #pragma unroll
            for (int ntl = 0; ntl < 2; ++ntl)
              pp[p][mtl][rr] = fmaf(qm[p][half*2 + ntl], acc[ntl][p*2+mtl][rr], pp[p][mtl][rr]);
          }
    }
    #pragma unroll
    for (int p = 0; p < 2; ++p) {
      float lg[2][4];
      #pragma unroll
      for (int mtl = 0; mtl < 2; ++mtl)
        #pragma unroll
        for (int rr = 0; rr < 4; ++rr) {
          float v = pp[p][mtl][rr];
          #pragma unroll
          for (int d = 1; d < 16; d <<= 1) v += __shfl_xor(v, d, 64);
          lg[mtl][rr] = v * 0.0625f;
        }
      float mx = -1e30f;
      #pragma unroll
      for (int mtl = 0; mtl < 2; ++mtl)
        #pragma unroll
        for (int rr = 0; rr < 4; ++rr) mx = fmaxf(mx, lg[mtl][rr]);
      mx = fmaxf(mx, __shfl_xor(mx, 16, 64));
      mx = fmaxf(mx, __shfl_xor(mx, 32, 64));
      float ssum = 0.f;
      #pragma unroll
      for (int mtl = 0; mtl < 2; ++mtl)
        #pragma unroll
        for (int rr = 0; rr < 4; ++rr) { aw[p][mtl][rr] = expf(lg[mtl][rr] - mx); ssum += aw[p][mtl][rr]; }
      ssum += __shfl_xor(ssum, 16, 64);
      ssum += __shfl_xor(ssum, 32, 64);
      inv[p] = 1.f / ssum;
    }
  }
  // pass V: two halves; outputs independent per ntl
  {
    #pragma unroll 1
    for (int half = 0; half < 2; ++half) {
      frag_cd acc[2][4] = {};
      for (int kt = 0; kt < 5; ++kt) {
        const int ko = kt*32 + quad*8;
        frag_ab a[4];
        #pragma unroll
        for (int mt = 0; mt < 4; ++mt)
          a[mt] = *(const frag_ab*)&Xs[(mt*16 + col)*XBS + ko];
        #pragma unroll
        for (int ntl = 0; ntl < 2; ++ntl) {
          const int nt = 32 + w*4 + half*2 + ntl;   // part 2
          const frag_ab bfr = *(const frag_ab*)(wfrag + ((size_t)(kt*48 + nt)*64 + lane)*8);
          #pragma unroll
          for (int mt = 0; mt < 4; ++mt)
            acc[ntl][mt] = __builtin_amdgcn_mfma_f32_16x16x32_bf16(a[mt], bfr, acc[ntl][mt], 0, 0, 0);
        }
      }
      #pragma unroll
      for (int p = 0; p < 2; ++p)
        #pragma unroll
        for (int ntl = 0; ntl < 2; ++ntl) {
          float o = 0.f;
          #pragma unroll
          for (int mtl = 0; mtl < 2; ++mtl)
            #pragma unroll
            for (int rr = 0; rr < 4; ++rr) o = fmaf(aw[p][mtl][rr], acc[ntl][p*2+mtl][rr], o);
          o += __shfl_xor(o, 16, 64);
          o += __shfl_xor(o, 32, 64);
          if (quad == 0)
            attnout[(size_t)(bp0+p)*Cn + w*64 + (half*2 + ntl)*16 + col] = f2b(o * inv[p]);
        }
    }
  }
}

// =====================================================================
// Kernel 3: MFMA GEMM, 64x128 tile (unchanged from r7/r8).
// =====================================================================
template<bool RELU, bool ADD_S, bool OUT_BF16>
__global__ __launch_bounds__(256) void mfma_gemm_kernel(
    const bf16* __restrict__ A, int lda, int Ka,
    const short* __restrict__ Wf, int nnt_total, int N,
    const float* __restrict__ bias, const bf16* __restrict__ S,
    void* __restrict__ Dv) {
  __shared__ __align__(16) short As[64*40];
  const int m0 = blockIdx.y * 64;
  const int n0 = blockIdx.x * 128;
  const int tid = threadIdx.x, lane = tid & 63, w = tid >> 6;
  const int col = lane & 15, quad = lane >> 4;
  const int row = tid >> 2, c8 = (tid & 3) * 8;
  frag_cd acc[4][2] = {};
  const int nkt = (Ka + 31) >> 5;
  for (int kt = 0; kt < nkt; ++kt) {
    const int k0 = kt*32 + c8;
    frag_ab av = {0,0,0,0,0,0,0,0};
    if (k0 + 8 <= Ka)
      av = *(const frag_ab*)((const short*)A + (size_t)(m0+row)*lda + k0);
    __syncthreads();
    *(frag_ab*)&As[row*40 + c8] = av;
    __syncthreads();
    frag_ab afr[4];
    #pragma unroll
    for (int mt = 0; mt < 4; ++mt)
      afr[mt] = *(const frag_ab*)&As[(mt*16 + col)*40 + quad*8];
    #pragma unroll
    for (int ntl = 0; ntl < 2; ++ntl) {
      const int nt = (n0 >> 4) + w*2 + ntl;
      const frag_ab bfr = *(const frag_ab*)(Wf + ((size_t)(kt*nnt_total + nt)*64 + lane)*8);
      #pragma unroll
      for (int mt = 0; mt < 4; ++mt)
        acc[mt][ntl] = __builtin_amdgcn_mfma_f32_16x16x32_bf16(afr[mt], bfr, acc[mt][ntl], 0, 0, 0);
    }
  }
  #pragma unroll
  for (int ntl = 0; ntl < 2; ++ntl) {
    const int n = n0 + w*32 + ntl*16 + col;
    const float bv = bias[n];
    #pragma unroll
    for (int mt = 0; mt < 4; ++mt) {
      #pragma unroll
      for (int r = 0; r < 4; ++r) {
        const int m = m0 + mt*16 + quad*4 + r;
        float v = acc[mt][ntl][r] + bv;
        if (RELU) v = fmaxf(v, 0.f);
        if (ADD_S) v += b2f(S[(size_t)m*N + n]);
        if (OUT_BF16) ((bf16*)Dv)[(size_t)m*N + n] = f2b(v);
        else          ((float*)Dv)[(size_t)m*N + n] = v;
      }
    }
  }
}

// =====================================================================
// Kernel 3b: dual GEMM (proj + dense fused), 64x128 tile, 512 blocks.
// =====================================================================
__global__ __launch_bounds__(256) void dual_gemm_kernel(
    const bf16* __restrict__ A1, const short* __restrict__ W1,
    const bf16* __restrict__ A2, const short* __restrict__ W2,
    const float* __restrict__ b1, const float* __restrict__ b2,
    bf16* __restrict__ D) {
  __shared__ __align__(16) short As[64*40];
  const int m0 = blockIdx.y * 64;
  const int n0 = blockIdx.x * 128;
  const int tid = threadIdx.x, lane = tid & 63, w = tid >> 6;
  const int col = lane & 15, quad = lane >> 4;
  const int row = tid >> 2, c8 = (tid & 3) * 8;
  frag_cd acc1[4][2] = {}, acc2[4][2] = {};
  for (int kt = 0; kt < 8; ++kt) {
    const frag_ab av = *(const frag_ab*)((const short*)A1 + (size_t)(m0+row)*Cn + kt*32 + c8);
    __syncthreads();
    *(frag_ab*)&As[row*40 + c8] = av;
    __syncthreads();
    frag_ab afr[4];
    #pragma unroll
    for (int mt = 0; mt < 4; ++mt)
      afr[mt] = *(const frag_ab*)&As[(mt*16 + col)*40 + quad*8];
    #pragma unroll
    for (int ntl = 0; ntl < 2; ++ntl) {
      const int nt = (n0 >> 4) + w*2 + ntl;
      const frag_ab bfr = *(const frag_ab*)(W1 + ((size_t)(kt*16 + nt)*64 + lane)*8);
      #pragma unroll
      for (int mt = 0; mt < 4; ++mt)
        acc1[mt][ntl] = __builtin_amdgcn_mfma_f32_16x16x32_bf16(afr[mt], bfr, acc1[mt][ntl], 0, 0, 0);
    }
  }
  for (int kt = 0; kt < 5; ++kt) {
    const int k0 = kt*32 + c8;
    frag_ab av = {0,0,0,0,0,0,0,0};
    if (k0 + 8 <= GFS)
      av = *(const frag_ab*)((const short*)A2 + (size_t)(m0+row)*GFS + k0);
    __syncthreads();
    *(frag_ab*)&As[row*40 + c8] = av;
    __syncthreads();
    frag_ab afr[4];
    #pragma unroll
    for (int mt = 0; mt < 4; ++mt)
      afr[mt] = *(const frag_ab*)&As[(mt*16 + col)*40 + quad*8];
    #pragma unroll
    for (int ntl = 0; ntl < 2; ++ntl) {
      const int nt = (n0 >> 4) + w*2 + ntl;
      const frag_ab bfr = *(const frag_ab*)(W2 + ((size_t)(kt*16 + nt)*64 + lane)*8);
      #pragma unroll
      for (int mt = 0; mt < 4; ++mt)
        acc2[mt][ntl] = __builtin_amdgcn_mfma_f32_16x16x32_bf16(afr[mt], bfr, acc2[mt][ntl], 0, 0, 0);
    }
  }
  #pragma unroll
  for (int ntl = 0; ntl < 2; ++ntl) {
    const int n = n0 + w*32 + ntl*16 + col;
    const float bv1 = b1[n], bv2 = b2[n];
    #pragma unroll
    for (int mt = 0; mt < 4; ++mt) {
      #pragma unroll
      for (int r = 0; r < 4; ++r) {
        const int m = m0 + mt*16 + quad*4 + r;
        const float v = fmaxf(acc1[mt][ntl][r] + bv1, 0.f)
                      + fmaxf(acc2[mt][ntl][r] + bv2, 0.f);
        D[(size_t)m*Cn + n] = f2b(v);
      }
    }
  }
}

// =====================================================================
// Kernel 4: LayerNorm2 over C=256, 4 rows/block (separate — measured
// faster than fusing into dual_gemm, r20 post-mortem).
// =====================================================================
__global__ __launch_bounds__(256) void ln2_kernel(const bf16* __restrict__ feat,
                                                  const float* __restrict__ g,
                                                  const float* __restrict__ b,
                                                  bf16* __restrict__ out) {
  const int r = blockIdx.x*4 + (threadIdx.x >> 6), lane = threadIdx.x & 63;
  float vv[4];
  #pragma unroll
  for (int c = 0; c < 4; ++c) vv[c] = b2f(feat[(size_t)r*Cn + lane*4 + c]);
  float s  = vv[0] + vv[1] + vv[2] + vv[3];
  float s2 = vv[0]*vv[0] + vv[1]*vv[1] + vv[2]*vv[2] + vv[3]*vv[3];
  #pragma unroll
  for (int d = 32; d; d >>= 1) { s += __shfl_xor(s, d, 64); s2 += __shfl_xor(s2, d, 64); }
  const float mean = s * (1.f/256.f);
  const float var  = s2 * (1.f/256.f) - mean*mean;
  const float rstd = rsqrtf(var + 1e-3f);
  #pragma unroll
  for (int c = 0; c < 4; ++c) {
    const int cc = lane*4 + c;
    out[(size_t)r*Cn + cc] = f2b((vv[c] - mean)*rstd*g[cc] + b[cc]);
  }
}

// =====================================================================
// kernel_launch — fp32 in/out. Workspace (peak 41.16 MB < 41.94 proven):
//   wqkv@0 245,760 | wproj@245,760 131,072 | wdense@376,832 81,920
//   wfc1@458,752 262,144 | wfc2@720,896 262,144 | pad to 1 MiB
//   featB  bf16 [16384*256] @  1,048,576   8 MiB  residual, live to end
//   attnA  bf16 [16384*256] @  9,437,184   8 MiB  attnout -> ln2out
//   gfmax  bf16 [16384*136] @ 17,825,792   4.46 MiB } dead before fc1
//   idx    int  [16384*32]  @ 22,282,240   2 MiB    } fc1out overlays
//   fc1out bf16 [16384*512] @ 24,379,392  16 MiB  (ends 41,156,608)
//   xyzw   f4   [65536]     @ 24,379,392   1 MiB  (lifetime: prep+knn
//                                                  only; fc1out written
//                                                  much later — no clash)
// =====================================================================
extern "C" void kernel_launch(void* const* d_in, const int* in_sizes, int n_in,
                              void* d_out, int out_size, void* d_ws, size_t ws_size,
                              hipStream_t stream) {
  const float* xyz     = (const float*)d_in[0];
  const float* newxyz  = (const float*)d_in[1];
  const float* featin  = (const float*)d_in[2];
  const float* w_qkv   = (const float*)d_in[3];
  const float* proj_w  = (const float*)d_in[4];
  const float* proj_b  = (const float*)d_in[5];
  const float* dense_w = (const float*)d_in[6];
  const float* dense_b = (const float*)d_in[7];
  const float* fc1_w   = (const float*)d_in[8];
  const float* fc1_b   = (const float*)d_in[9];
  const float* fc2_w   = (const float*)d_in[10];
  const float* fc2_b   = (const float*)d_in[11];
  const float* n1g     = (const float*)d_in[12];
  const float* n1b     = (const float*)d_in[13];
  const float* n2g     = (const float*)d_in[14];
  const float* n2b     = (const float*)d_in[15];

  char*  ws     = (char*)d_ws;
  short* wqkv   = (short*)(ws + 0);
  short* wproj  = (short*)(ws + 245760);
  short* wdense = (short*)(ws + 376832);
  short* wfc1   = (short*)(ws + 458752);
  short* wfc2   = (short*)(ws + 720896);
  bf16*  featB  = (bf16*)(ws + 1048576);
  bf16*  attnA  = (bf16*)(ws + 9437184);
  bf16*  gfmax  = (bf16*)(ws + 17825792);
  int*   idxws  = (int*) (ws + 22282240);
  bf16*  fc1out = (bf16*)(ws + 24379392);
  float4* xyzw  = (float4*)(ws + 24379392);   // overlays fc1out (disjoint lifetime)

  const int M = Bn * NPn;  // 16384

  xyzw_prep_kernel<<<dim3(Bn*Nn/256), dim3(256), 0, stream>>>(xyz, xyzw);
  knn_kernel<<<dim3(M), dim3(256), 0, stream>>>(xyzw, newxyz, idxws);
  wprep_all_kernel<<<dim3(1920), dim3(256), 0, stream>>>(
      w_qkv, proj_w, dense_w, fc1_w, fc2_w, wqkv, wproj, wdense, wfc1, wfc2);

  fused_attn_kernel<<<dim3(M/2), dim3(256), 0, stream>>>(
      xyz, newxyz, featin, wqkv, n1g, n1b, idxws, attnA, gfmax);
  // featB = relu(attn@proj + pb) + relu(gfmax@dense + db)
  dual_gemm_kernel<<<dim3(2, M/64), dim3(256), 0, stream>>>(
      attnA, wproj, gfmax, wdense, proj_b, dense_b, featB);
  // attnA <- LN2(featB)
  ln2_kernel<<<dim3(M/4), dim3(256), 0, stream>>>(featB, n2g, n2b, attnA);
  // fc1out = relu(attnA @ fc1 + b1)
  mfma_gemm_kernel<true, false, true><<<dim3(4, M/64), dim3(256), 0, stream>>>(
      attnA, Cn, Cn, wfc1, 32, 512, fc1_b, (const bf16*)nullptr, fc1out);
  // out = fc1out @ fc2 + b2 + featB   (fp32 output)
  mfma_gemm_kernel<false, true, false><<<dim3(2, M/64), dim3(256), 0, stream>>>(
      fc1out, 512, 512, wfc2, 16, Cn, fc2_b, featB, d_out);
}